// Round 4
// baseline (151.807 us; speedup 1.0000x reference)
//
#include <hip/hip_runtime.h>
#include <hip/hip_bf16.h>

#define NN 4096
#define IN_DIM 512
#define OUT_D 64
#define LOG2E 1.44269504088896340736f

typedef __attribute__((ext_vector_type(8))) short short8v;
typedef __attribute__((ext_vector_type(4))) float f32x4;

__device__ __forceinline__ short to_bf16_rne(float x) {
  unsigned u = __builtin_bit_cast(unsigned, x);
  u = (u + 0x7FFFu + ((u >> 16) & 1u)) >> 16;
  return (short)u;
}
__device__ __forceinline__ float bf16_to_f(short h) {
  unsigned u = ((unsigned)(unsigned short)h) << 16;
  return __builtin_bit_cast(float, u);
}
// order-preserving float<->uint key for atomicMax
__device__ __forceinline__ unsigned fkey(float f) {
  unsigned u = __builtin_bit_cast(unsigned, f);
  return u ^ ((unsigned)((int)u >> 31) | 0x80000000u);
}
__device__ __forceinline__ float funkey(unsigned k) {
  unsigned u = (k >> 31) ? (k ^ 0x80000000u) : ~k;
  return __builtin_bit_cast(float, u);
}

// ---------------- Kernel 0: pack W^T into A-fragment layout (hi/lo);
// init s2key + per-rowblock completion counters (ws is re-poisoned every call!)
__global__ __launch_bounds__(256) void k_wpack(
    const float* __restrict__ W, short* __restrict__ Ahi, short* __restrict__ Alo,
    unsigned* __restrict__ s2key, int* __restrict__ cnt)
{
  int tid = blockIdx.x * 256 + threadIdx.x;   // 0..4095
  if (blockIdx.x == 0) {
    if (threadIdx.x == 0) *s2key = 0u;
    if (threadIdx.x < NN / 64) cnt[threadIdx.x] = 0;
  }
  int l = tid & 63, t = (tid >> 6) & 15, m = tid >> 10;
  int dd = m * 16 + (l & 15);
  int kbase = t * 32 + 8 * (l >> 4);
  short8v hi, lo;
  #pragma unroll
  for (int r = 0; r < 8; ++r) {
    float w = W[(size_t)(kbase + r) * OUT_D + dd];
    short h = to_bf16_rne(w);
    hi[r] = h;
    lo[r] = to_bf16_rne(w - bf16_to_f(h));
  }
  *(short8v*)(Ahi + (size_t)tid * 8) = hi;
  *(short8v*)(Alo + (size_t)tid * 8) = lo;
}

// ---------------- Kernel 1: fused X->bf16(hi/lo) LDS staging + h^T MFMA ----------------
__global__ __launch_bounds__(256) void k_h_mfma(
    const float* __restrict__ X,
    const short* __restrict__ Ahi, const short* __restrict__ Alo,
    const float* __restrict__ a,
    short* __restrict__ hbT, float* __restrict__ s1, float* __restrict__ s2,
    unsigned* __restrict__ s2key)
{
  __shared__ short xhi[16 * 512];   // 16 KB, XOR-swizzled 16B chunks
  __shared__ short xlo[16 * 512];
  __shared__ float sm1[4][16], sm2[4][16];
  int tid = threadIdx.x;
  int m = tid >> 6, l = tid & 63, lo = l & 15, g = l >> 4;
  int row0 = blockIdx.x * 16;

  #pragma unroll
  for (int i = 0; i < 4; ++i) {
    int flat = i * 2048 + tid * 8;
    int r = flat >> 9, k = flat & 511;
    float f[8];
    *(float4*)(f)     = *(const float4*)(X + (size_t)row0 * IN_DIM + flat);
    *(float4*)(f + 4) = *(const float4*)(X + (size_t)row0 * IN_DIM + flat + 4);
    short8v hi, lov;
    #pragma unroll
    for (int q = 0; q < 8; ++q) {
      short h = to_bf16_rne(f[q]);
      hi[q] = h;
      lov[q] = to_bf16_rne(f[q] - bf16_to_f(h));
    }
    int chunk = k >> 3;
    int dst = (r << 9) + ((chunk ^ (r & 7)) << 3);
    *(short8v*)(xhi + dst) = hi;
    *(short8v*)(xlo + dst) = lov;
  }
  __syncthreads();

  f32x4 acc = {0.f, 0.f, 0.f, 0.f};
  const short* ah = Ahi + ((size_t)(m * 16) * 64 + l) * 8;
  const short* al = Alo + ((size_t)(m * 16) * 64 + l) * 8;
  #pragma unroll
  for (int t = 0; t < 16; ++t) {
    int c = t * 4 + g;
    int src = (lo << 9) + ((c ^ (lo & 7)) << 3);
    short8v bhi = *(const short8v*)(xhi + src);
    short8v blo = *(const short8v*)(xlo + src);
    short8v fhi = *(const short8v*)(ah + (size_t)t * 64 * 8);
    short8v flo = *(const short8v*)(al + (size_t)t * 64 * 8);
    acc = __builtin_amdgcn_mfma_f32_16x16x32_bf16(fhi, bhi, acc, 0, 0, 0);
    acc = __builtin_amdgcn_mfma_f32_16x16x32_bf16(fhi, blo, acc, 0, 0, 0);
    acc = __builtin_amdgcn_mfma_f32_16x16x32_bf16(flo, bhi, acc, 0, 0, 0);
  }

  float p1 = 0.f, p2 = 0.f;
  #pragma unroll
  for (int q = 0; q < 4; ++q) {
    int d = m * 16 + 4 * g + q;
    hbT[(size_t)d * NN + row0 + lo] = to_bf16_rne(acc[q]);
    p1 = fmaf(acc[q], a[d], p1);
    p2 = fmaf(acc[q], a[OUT_D + d], p2);
  }
  p1 += __shfl_xor(p1, 16); p1 += __shfl_xor(p1, 32);
  p2 += __shfl_xor(p2, 16); p2 += __shfl_xor(p2, 32);
  if (l < 16) { sm1[m][l] = p1; sm2[m][l] = p2; }
  __syncthreads();
  if (tid < 16) {
    float v1 = (sm1[0][tid] + sm1[1][tid] + sm1[2][tid] + sm1[3][tid]) * LOG2E;
    float v2 = (sm2[0][tid] + sm2[1][tid] + sm2[2][tid] + sm2[3][tid]) * LOG2E;
    s1[row0 + tid] = v1;
    s2[row0 + tid] = v2;
    float v = v2;
    #pragma unroll
    for (int off = 8; off >= 1; off >>= 1) v = fmaxf(v, __shfl_xor(v, off));
    if (tid == 0) atomicMax(s2key, fkey(v));
  }
}

// ---------------- Kernel 3: fused masked-softmax-weight + P@H + last-block combine ----
// Wave = 16-row M-tile; block = 4 waves = 64 rows; grid = (NN/64, NPART).
template<int JCHUNK>
__global__ __launch_bounds__(256) void k_attn(
    const int* __restrict__ adj, const short* __restrict__ hbT,
    const float* __restrict__ s1, const float* __restrict__ s2,
    const unsigned* __restrict__ s2keyp,
    float* __restrict__ accp, float* __restrict__ lpart,
    int* __restrict__ cnt, float* __restrict__ out)
{
  constexpr int NIT = JCHUNK / 32;
  __shared__ int sflag;
  __shared__ float srcp[64];
  int w  = threadIdx.x >> 6;
  int l  = threadIdx.x & 63;
  int lo = l & 15, g = l >> 4;
  int part  = blockIdx.y;
  int ibase = blockIdx.x * 64 + w * 16;
  int row   = ibase + lo;

  float s1v = s1[row];
  float x = s1v + funkey(*s2keyp);
  float M = fmaxf(x, 0.01f * x);   // row-constant upper bound on all (scaled) scores

  f32x4 c0 = {0.f,0.f,0.f,0.f}, c1 = {0.f,0.f,0.f,0.f};
  f32x4 c2 = {0.f,0.f,0.f,0.f}, c3 = {0.f,0.f,0.f,0.f};
  float lsum = 0.f;

  const int* adjrow = adj + (size_t)row * NN;
  int jj = part * JCHUNK + g * 8;

  int4 pa0[2], pa1[2]; float4 ps0[2], ps1[2];
  #pragma unroll
  for (int p = 0; p < 2; ++p) {
    int j = jj + p * 32;
    pa0[p] = *(const int4*)(adjrow + j);
    pa1[p] = *(const int4*)(adjrow + j + 4);
    ps0[p] = *(const float4*)(s2 + j);
    ps1[p] = *(const float4*)(s2 + j + 4);
  }

  #pragma unroll
  for (int it = 0; it < NIT; ++it) {
    const int buf = it & 1;
    int4 a0 = pa0[buf], a1 = pa1[buf];
    float4 t0 = ps0[buf], t1 = ps1[buf];
    if (it + 2 < NIT) {                 // 2-deep prefetch
      int j = jj + (it + 2) * 32;
      pa0[buf] = *(const int4*)(adjrow + j);
      pa1[buf] = *(const int4*)(adjrow + j + 4);
      ps0[buf] = *(const float4*)(s2 + j);
      ps1[buf] = *(const float4*)(s2 + j + 4);
    }
    int jc = jj + it * 32;

    short8v b0 = *(const short8v*)(hbT + ((size_t)(lo)      << 12) + jc);
    short8v b1 = *(const short8v*)(hbT + ((size_t)(16 + lo) << 12) + jc);
    short8v b2 = *(const short8v*)(hbT + ((size_t)(32 + lo) << 12) + jc);
    short8v b3 = *(const short8v*)(hbT + ((size_t)(48 + lo) << 12) + jc);

    int av[8]; float sv[8];
    *(int4*)(av) = a0;  *(int4*)(av + 4) = a1;
    *(float4*)(sv) = t0; *(float4*)(sv + 4) = t1;

    short8v af;
    #pragma unroll
    for (int r = 0; r < 8; ++r) {
      float y = s1v + sv[r];
      float e = fmaxf(y, 0.01f * y);    // leaky-relu (log2-scaled domain)
      float p = exp2f(e - M);
      p = (av[r] > 0) ? p : 0.f;
      lsum += p;
      af[r] = to_bf16_rne(p);
    }

    c0 = __builtin_amdgcn_mfma_f32_16x16x32_bf16(af, b0, c0, 0, 0, 0);
    c1 = __builtin_amdgcn_mfma_f32_16x16x32_bf16(af, b1, c1, 0, 0, 0);
    c2 = __builtin_amdgcn_mfma_f32_16x16x32_bf16(af, b2, c2, 0, 0, 0);
    c3 = __builtin_amdgcn_mfma_f32_16x16x32_bf16(af, b3, c3, 0, 0, 0);
  }

  lsum += __shfl_xor(lsum, 16);
  lsum += __shfl_xor(lsum, 32);
  if (l < 16) lpart[(size_t)part * NN + ibase + l] = lsum;

  // C/D layout: col = lane&15, row = (lane>>4)*4 + reg
  float* ap = accp + ((size_t)part * NN + ibase) * OUT_D;
  #pragma unroll
  for (int q = 0; q < 4; ++q) {
    int ri = g * 4 + q;
    ap[ri * OUT_D +  0 + lo] = c0[q];
    ap[ri * OUT_D + 16 + lo] = c1[q];
    ap[ri * OUT_D + 32 + lo] = c2[q];
    ap[ri * OUT_D + 48 + lo] = c3[q];
  }

  // ---- last-block combine (threadFenceReduction pattern) ----
  __syncthreads();
  if (threadIdx.x == 0) {
    __threadfence();                                  // release our stores
    int old = atomicAdd(&cnt[blockIdx.x], 1);
    sflag = (old == (int)gridDim.y - 1);
  }
  __syncthreads();
  if (!sflag) return;
  __threadfence();                                    // acquire others' stores

  int npart = gridDim.y;
  if (threadIdx.x < 64) {
    float li = 0.f;
    for (int p = 0; p < npart; ++p)
      li += lpart[(size_t)p * NN + blockIdx.x * 64 + threadIdx.x];
    srcp[threadIdx.x] = 1.0f / li;
  }
  __syncthreads();
  int base = blockIdx.x * 64 * OUT_D;
  #pragma unroll 4
  for (int t = 0; t < 16; ++t) {
    int idx = t * 256 + threadIdx.x;
    float s = 0.f;
    for (int p = 0; p < npart; ++p)
      s += accp[(size_t)p * (NN * OUT_D) + base + idx];
    out[base + idx] = s * srcp[idx >> 6];
  }
}

// runtime-jchunk fallback (small workspaces only)
__global__ __launch_bounds__(256) void k_attn_rt(
    const int* __restrict__ adj, const short* __restrict__ hbT,
    const float* __restrict__ s1, const float* __restrict__ s2,
    const unsigned* __restrict__ s2keyp,
    float* __restrict__ accp, float* __restrict__ lpart, int jchunk)
{
  int w  = threadIdx.x >> 6;
  int l  = threadIdx.x & 63;
  int lo = l & 15, g = l >> 4;
  int part  = blockIdx.y;
  int ibase = blockIdx.x * 64 + w * 16;
  int row   = ibase + lo;
  float s1v = s1[row];
  float x = s1v + funkey(*s2keyp);
  float M = fmaxf(x, 0.01f * x);
  f32x4 c0 = {0.f,0.f,0.f,0.f}, c1 = {0.f,0.f,0.f,0.f};
  f32x4 c2 = {0.f,0.f,0.f,0.f}, c3 = {0.f,0.f,0.f,0.f};
  float lsum = 0.f;
  const int* adjrow = adj + (size_t)row * NN;
  int jj = part * jchunk + g * 8;
  for (int js = 0; js < jchunk; js += 32, jj += 32) {
    int4 a0 = *(const int4*)(adjrow + jj);
    int4 a1 = *(const int4*)(adjrow + jj + 4);
    float4 t0 = *(const float4*)(s2 + jj);
    float4 t1 = *(const float4*)(s2 + jj + 4);
    short8v b0 = *(const short8v*)(hbT + ((size_t)(lo)      << 12) + jj);
    short8v b1 = *(const short8v*)(hbT + ((size_t)(16 + lo) << 12) + jj);
    short8v b2 = *(const short8v*)(hbT + ((size_t)(32 + lo) << 12) + jj);
    short8v b3 = *(const short8v*)(hbT + ((size_t)(48 + lo) << 12) + jj);
    int av[8]; float sv[8];
    *(int4*)(av) = a0;  *(int4*)(av + 4) = a1;
    *(float4*)(sv) = t0; *(float4*)(sv + 4) = t1;
    short8v af;
    #pragma unroll
    for (int r = 0; r < 8; ++r) {
      float y = s1v + sv[r];
      float e = fmaxf(y, 0.01f * y);
      float p = exp2f(e - M);
      p = (av[r] > 0) ? p : 0.f;
      lsum += p;
      af[r] = to_bf16_rne(p);
    }
    c0 = __builtin_amdgcn_mfma_f32_16x16x32_bf16(af, b0, c0, 0, 0, 0);
    c1 = __builtin_amdgcn_mfma_f32_16x16x32_bf16(af, b1, c1, 0, 0, 0);
    c2 = __builtin_amdgcn_mfma_f32_16x16x32_bf16(af, b2, c2, 0, 0, 0);
    c3 = __builtin_amdgcn_mfma_f32_16x16x32_bf16(af, b3, c3, 0, 0, 0);
  }
  lsum += __shfl_xor(lsum, 16);
  lsum += __shfl_xor(lsum, 32);
  if (l < 16) lpart[(size_t)part * NN + ibase + l] = lsum;
  float* ap = accp + ((size_t)part * NN + ibase) * OUT_D;
  #pragma unroll
  for (int q = 0; q < 4; ++q) {
    int ri = g * 4 + q;
    ap[ri * OUT_D +  0 + lo] = c0[q];
    ap[ri * OUT_D + 16 + lo] = c1[q];
    ap[ri * OUT_D + 32 + lo] = c2[q];
    ap[ri * OUT_D + 48 + lo] = c3[q];
  }
}

// ---------------- Kernel 4: combine (fallback path only) ----------------
__global__ __launch_bounds__(256) void k_combine(
    const float* __restrict__ accp, const float* __restrict__ lpart,
    float* __restrict__ out, int npart)
{
  int idx = blockIdx.x * 256 + threadIdx.x;
  int i = idx >> 6;
  float s = 0.f, li = 0.f;
  for (int p = 0; p < npart; ++p) {
    s  += accp[(size_t)p * (NN * OUT_D) + idx];
    li += lpart[(size_t)p * NN + i];
  }
  out[idx] = s / li;
}

extern "C" void kernel_launch(void* const* d_in, const int* in_sizes, int n_in,
                              void* d_out, int out_size, void* d_ws, size_t ws_size,
                              hipStream_t stream)
{
  const float* X   = (const float*)d_in[0];
  const int*   adj = (const int*)d_in[1];
  const float* W   = (const float*)d_in[2];
  const float* a   = (const float*)d_in[3];
  float* out = (float*)d_out;

  char* ws = (char*)d_ws;
  size_t off = 0;
  float* s1  = (float*)(ws + off); off += NN * 4;
  float* s2  = (float*)(ws + off); off += NN * 4;
  unsigned* s2key = (unsigned*)(ws + off); off += 64;
  int* cnt   = (int*)(ws + off); off += (NN / 64) * 4;
  off = (off + 63) & ~(size_t)63;
  short* hbT = (short*)(ws + off); off += (size_t)OUT_D * NN * 2;   // 512 KB
  short* Ahi = (short*)(ws + off); off += 4096 * 8 * 2;             // 64 KB
  short* Alo = (short*)(ws + off); off += 4096 * 8 * 2;             // 64 KB
  size_t fixed = off;

  size_t per_part = (size_t)(NN * OUT_D + NN) * 4;
  int npart = 1;
  for (int p = 16; p >= 1; p >>= 1)
    if (fixed + (size_t)p * per_part <= ws_size) { npart = p; break; }
  float* accp  = (float*)(ws + fixed);
  float* lpart = (float*)(ws + fixed + (size_t)npart * NN * OUT_D * 4);

  k_wpack<<<16, 256, 0, stream>>>(W, Ahi, Alo, s2key, cnt);
  k_h_mfma<<<NN / 16, 256, 0, stream>>>(X, Ahi, Alo, a, hbT, s1, s2, s2key);
  dim3 grid_attn(NN / 64, npart);
  if (npart == 16) {
    k_attn<256><<<grid_attn, 256, 0, stream>>>(adj, hbT, s1, s2, s2key, accp, lpart, cnt, out);
  } else if (npart == 8) {
    k_attn<512><<<grid_attn, 256, 0, stream>>>(adj, hbT, s1, s2, s2key, accp, lpart, cnt, out);
  } else {
    k_attn_rt<<<grid_attn, 256, 0, stream>>>(adj, hbT, s1, s2, s2key, accp, lpart, NN / npart);
    k_combine<<<(NN * OUT_D) / 256, 256, 0, stream>>>(accp, lpart, out, npart);
  }
}

// Round 5
// 54.012 us; speedup vs baseline: 2.8106x; 2.8106x over previous
//
#include <hip/hip_runtime.h>
#include <hip/hip_bf16.h>

#define NN 4096
#define IN_DIM 512
#define OUT_D 64
#define LOG2E 1.44269504088896340736f

typedef __attribute__((ext_vector_type(8))) short short8v;
typedef __attribute__((ext_vector_type(4))) float f32x4;

__device__ __forceinline__ short to_bf16_rne(float x) {
  unsigned u = __builtin_bit_cast(unsigned, x);
  u = (u + 0x7FFFu + ((u >> 16) & 1u)) >> 16;
  return (short)u;
}
__device__ __forceinline__ float bf16_to_f(short h) {
  unsigned u = ((unsigned)(unsigned short)h) << 16;
  return __builtin_bit_cast(float, u);
}
// order-preserving float<->uint key for atomicMax
__device__ __forceinline__ unsigned fkey(float f) {
  unsigned u = __builtin_bit_cast(unsigned, f);
  return u ^ ((unsigned)((int)u >> 31) | 0x80000000u);
}
__device__ __forceinline__ float funkey(unsigned k) {
  unsigned u = (k >> 31) ? (k ^ 0x80000000u) : ~k;
  return __builtin_bit_cast(float, u);
}

// ---------------- Kernel 0: pack W^T into A-fragment layout (hi/lo); init s2key ----
// Apack[m][t][l][r] = W[t*32 + 8*(l>>4) + r][m*16 + (l&15)]
__global__ __launch_bounds__(256) void k_wpack(
    const float* __restrict__ W, short* __restrict__ Ahi, short* __restrict__ Alo,
    unsigned* __restrict__ s2key)
{
  int tid = blockIdx.x * 256 + threadIdx.x;   // 0..4095
  if (tid == 0) *s2key = 0u;                  // ws re-poisoned every call: must re-init
  int l = tid & 63, t = (tid >> 6) & 15, m = tid >> 10;
  int dd = m * 16 + (l & 15);
  int kbase = t * 32 + 8 * (l >> 4);
  short8v hi, lo;
  #pragma unroll
  for (int r = 0; r < 8; ++r) {
    float w = W[(size_t)(kbase + r) * OUT_D + dd];
    short h = to_bf16_rne(w);
    hi[r] = h;
    lo[r] = to_bf16_rne(w - bf16_to_f(h));
  }
  *(short8v*)(Ahi + (size_t)tid * 8) = hi;
  *(short8v*)(Alo + (size_t)tid * 8) = lo;
}

// ---------------- Kernel 1: fused X->bf16(hi/lo) LDS staging + h^T MFMA ----------------
// 256 blocks x 16 rows; 4 waves, wave m owns d-tile m. Writes hbT, s1, s2, s2key(max).
__global__ __launch_bounds__(256) void k_h_mfma(
    const float* __restrict__ X,
    const short* __restrict__ Ahi, const short* __restrict__ Alo,
    const float* __restrict__ a,
    short* __restrict__ hbT, float* __restrict__ s1, float* __restrict__ s2,
    unsigned* __restrict__ s2key)
{
  __shared__ short xhi[16 * 512];   // 16 KB, XOR-swizzled 16B chunks
  __shared__ short xlo[16 * 512];
  __shared__ float sm1[4][16], sm2[4][16];
  int tid = threadIdx.x;
  int m = tid >> 6, l = tid & 63, lo = l & 15, g = l >> 4;
  int row0 = blockIdx.x * 16;

  #pragma unroll
  for (int i = 0; i < 4; ++i) {
    int flat = i * 2048 + tid * 8;
    int r = flat >> 9, k = flat & 511;
    float f[8];
    *(float4*)(f)     = *(const float4*)(X + (size_t)row0 * IN_DIM + flat);
    *(float4*)(f + 4) = *(const float4*)(X + (size_t)row0 * IN_DIM + flat + 4);
    short8v hi, lov;
    #pragma unroll
    for (int q = 0; q < 8; ++q) {
      short h = to_bf16_rne(f[q]);
      hi[q] = h;
      lov[q] = to_bf16_rne(f[q] - bf16_to_f(h));
    }
    int chunk = k >> 3;
    int dst = (r << 9) + ((chunk ^ (r & 7)) << 3);
    *(short8v*)(xhi + dst) = hi;
    *(short8v*)(xlo + dst) = lov;
  }
  __syncthreads();

  f32x4 acc = {0.f, 0.f, 0.f, 0.f};
  const short* ah = Ahi + ((size_t)(m * 16) * 64 + l) * 8;
  const short* al = Alo + ((size_t)(m * 16) * 64 + l) * 8;
  #pragma unroll
  for (int t = 0; t < 16; ++t) {
    int c = t * 4 + g;
    int src = (lo << 9) + ((c ^ (lo & 7)) << 3);
    short8v bhi = *(const short8v*)(xhi + src);
    short8v blo = *(const short8v*)(xlo + src);
    short8v fhi = *(const short8v*)(ah + (size_t)t * 64 * 8);
    short8v flo = *(const short8v*)(al + (size_t)t * 64 * 8);
    acc = __builtin_amdgcn_mfma_f32_16x16x32_bf16(fhi, bhi, acc, 0, 0, 0);
    acc = __builtin_amdgcn_mfma_f32_16x16x32_bf16(fhi, blo, acc, 0, 0, 0);
    acc = __builtin_amdgcn_mfma_f32_16x16x32_bf16(flo, bhi, acc, 0, 0, 0);
  }

  // C layout: col(=row of X) = l&15, row(=d within tile) = 4*g + q
  float p1 = 0.f, p2 = 0.f;
  #pragma unroll
  for (int q = 0; q < 4; ++q) {
    int d = m * 16 + 4 * g + q;
    hbT[(size_t)d * NN + row0 + lo] = to_bf16_rne(acc[q]);
    p1 = fmaf(acc[q], a[d], p1);
    p2 = fmaf(acc[q], a[OUT_D + d], p2);
  }
  p1 += __shfl_xor(p1, 16); p1 += __shfl_xor(p1, 32);
  p2 += __shfl_xor(p2, 16); p2 += __shfl_xor(p2, 32);
  if (l < 16) { sm1[m][l] = p1; sm2[m][l] = p2; }
  __syncthreads();
  if (tid < 16) {
    float v1 = (sm1[0][tid] + sm1[1][tid] + sm1[2][tid] + sm1[3][tid]) * LOG2E;
    float v2 = (sm2[0][tid] + sm2[1][tid] + sm2[2][tid] + sm2[3][tid]) * LOG2E;
    s1[row0 + tid] = v1;
    s2[row0 + tid] = v2;
    float v = v2;
    #pragma unroll
    for (int off = 8; off >= 1; off >>= 1) v = fmaxf(v, __shfl_xor(v, off));
    if (tid == 0) atomicMax(s2key, fkey(v));
  }
}

// ---------------- Kernel 3: fused masked-softmax-weight + P@H via MFMA ----------------
// Wave = 16-row M-tile; block = 4 waves = 64 rows; grid = (NN/64, NPART).
// Compile-time JCHUNK -> full unroll, 2-deep adj/s2 prefetch with static indices.
// NO device fences / no cross-block communication here (R4 lesson: 10x regression).
template<int JCHUNK>
__global__ __launch_bounds__(256) void k_attn(
    const int* __restrict__ adj, const short* __restrict__ hbT,
    const float* __restrict__ s1, const float* __restrict__ s2,
    const unsigned* __restrict__ s2keyp,
    float* __restrict__ accp, float* __restrict__ lpart)
{
  constexpr int NIT = JCHUNK / 32;
  int w  = threadIdx.x >> 6;
  int l  = threadIdx.x & 63;
  int lo = l & 15, g = l >> 4;
  int part  = blockIdx.y;
  int ibase = blockIdx.x * 64 + w * 16;
  int row   = ibase + lo;

  float s1v = s1[row];
  float x = s1v + funkey(*s2keyp);
  float M = fmaxf(x, 0.01f * x);   // row-constant upper bound on all (scaled) scores

  f32x4 c0 = {0.f,0.f,0.f,0.f}, c1 = {0.f,0.f,0.f,0.f};
  f32x4 c2 = {0.f,0.f,0.f,0.f}, c3 = {0.f,0.f,0.f,0.f};
  float lsum = 0.f;

  const int* adjrow = adj + (size_t)row * NN;
  int jj = part * JCHUNK + g * 8;

  int4 pa0[2], pa1[2]; float4 ps0[2], ps1[2];
  #pragma unroll
  for (int p = 0; p < 2; ++p) {
    int j = jj + p * 32;
    pa0[p] = *(const int4*)(adjrow + j);
    pa1[p] = *(const int4*)(adjrow + j + 4);
    ps0[p] = *(const float4*)(s2 + j);
    ps1[p] = *(const float4*)(s2 + j + 4);
  }

  #pragma unroll
  for (int it = 0; it < NIT; ++it) {
    const int buf = it & 1;
    int4 a0 = pa0[buf], a1 = pa1[buf];
    float4 t0 = ps0[buf], t1 = ps1[buf];
    if (it + 2 < NIT) {                 // 2-deep prefetch
      int j = jj + (it + 2) * 32;
      pa0[buf] = *(const int4*)(adjrow + j);
      pa1[buf] = *(const int4*)(adjrow + j + 4);
      ps0[buf] = *(const float4*)(s2 + j);
      ps1[buf] = *(const float4*)(s2 + j + 4);
    }
    int jc = jj + it * 32;

    short8v b0 = *(const short8v*)(hbT + ((size_t)(lo)      << 12) + jc);
    short8v b1 = *(const short8v*)(hbT + ((size_t)(16 + lo) << 12) + jc);
    short8v b2 = *(const short8v*)(hbT + ((size_t)(32 + lo) << 12) + jc);
    short8v b3 = *(const short8v*)(hbT + ((size_t)(48 + lo) << 12) + jc);

    int av[8]; float sv[8];
    *(int4*)(av) = a0;  *(int4*)(av + 4) = a1;
    *(float4*)(sv) = t0; *(float4*)(sv + 4) = t1;

    short8v af;
    #pragma unroll
    for (int r = 0; r < 8; ++r) {
      float y = s1v + sv[r];
      float e = fmaxf(y, 0.01f * y);    // leaky-relu (log2-scaled domain)
      float p = exp2f(e - M);
      p = (av[r] > 0) ? p : 0.f;
      lsum += p;
      af[r] = to_bf16_rne(p);
    }

    c0 = __builtin_amdgcn_mfma_f32_16x16x32_bf16(af, b0, c0, 0, 0, 0);
    c1 = __builtin_amdgcn_mfma_f32_16x16x32_bf16(af, b1, c1, 0, 0, 0);
    c2 = __builtin_amdgcn_mfma_f32_16x16x32_bf16(af, b2, c2, 0, 0, 0);
    c3 = __builtin_amdgcn_mfma_f32_16x16x32_bf16(af, b3, c3, 0, 0, 0);
  }

  lsum += __shfl_xor(lsum, 16);
  lsum += __shfl_xor(lsum, 32);
  if (l < 16) lpart[(size_t)part * NN + ibase + l] = lsum;

  // C/D layout: col = lane&15, row = (lane>>4)*4 + reg
  float* ap = accp + ((size_t)part * NN + ibase) * OUT_D;
  #pragma unroll
  for (int q = 0; q < 4; ++q) {
    int ri = g * 4 + q;
    ap[ri * OUT_D +  0 + lo] = c0[q];
    ap[ri * OUT_D + 16 + lo] = c1[q];
    ap[ri * OUT_D + 32 + lo] = c2[q];
    ap[ri * OUT_D + 48 + lo] = c3[q];
  }
}

// runtime-jchunk fallback (small workspaces only)
__global__ __launch_bounds__(256) void k_attn_rt(
    const int* __restrict__ adj, const short* __restrict__ hbT,
    const float* __restrict__ s1, const float* __restrict__ s2,
    const unsigned* __restrict__ s2keyp,
    float* __restrict__ accp, float* __restrict__ lpart, int jchunk)
{
  int w  = threadIdx.x >> 6;
  int l  = threadIdx.x & 63;
  int lo = l & 15, g = l >> 4;
  int part  = blockIdx.y;
  int ibase = blockIdx.x * 64 + w * 16;
  int row   = ibase + lo;
  float s1v = s1[row];
  float x = s1v + funkey(*s2keyp);
  float M = fmaxf(x, 0.01f * x);
  f32x4 c0 = {0.f,0.f,0.f,0.f}, c1 = {0.f,0.f,0.f,0.f};
  f32x4 c2 = {0.f,0.f,0.f,0.f}, c3 = {0.f,0.f,0.f,0.f};
  float lsum = 0.f;
  const int* adjrow = adj + (size_t)row * NN;
  int jj = part * jchunk + g * 8;
  for (int js = 0; js < jchunk; js += 32, jj += 32) {
    int4 a0 = *(const int4*)(adjrow + jj);
    int4 a1 = *(const int4*)(adjrow + jj + 4);
    float4 t0 = *(const float4*)(s2 + jj);
    float4 t1 = *(const float4*)(s2 + jj + 4);
    short8v b0 = *(const short8v*)(hbT + ((size_t)(lo)      << 12) + jj);
    short8v b1 = *(const short8v*)(hbT + ((size_t)(16 + lo) << 12) + jj);
    short8v b2 = *(const short8v*)(hbT + ((size_t)(32 + lo) << 12) + jj);
    short8v b3 = *(const short8v*)(hbT + ((size_t)(48 + lo) << 12) + jj);
    int av[8]; float sv[8];
    *(int4*)(av) = a0;  *(int4*)(av + 4) = a1;
    *(float4*)(sv) = t0; *(float4*)(sv + 4) = t1;
    short8v af;
    #pragma unroll
    for (int r = 0; r < 8; ++r) {
      float y = s1v + sv[r];
      float e = fmaxf(y, 0.01f * y);
      float p = exp2f(e - M);
      p = (av[r] > 0) ? p : 0.f;
      lsum += p;
      af[r] = to_bf16_rne(p);
    }
    c0 = __builtin_amdgcn_mfma_f32_16x16x32_bf16(af, b0, c0, 0, 0, 0);
    c1 = __builtin_amdgcn_mfma_f32_16x16x32_bf16(af, b1, c1, 0, 0, 0);
    c2 = __builtin_amdgcn_mfma_f32_16x16x32_bf16(af, b2, c2, 0, 0, 0);
    c3 = __builtin_amdgcn_mfma_f32_16x16x32_bf16(af, b3, c3, 0, 0, 0);
  }
  lsum += __shfl_xor(lsum, 16);
  lsum += __shfl_xor(lsum, 32);
  if (l < 16) lpart[(size_t)part * NN + ibase + l] = lsum;
  float* ap = accp + ((size_t)part * NN + ibase) * OUT_D;
  #pragma unroll
  for (int q = 0; q < 4; ++q) {
    int ri = g * 4 + q;
    ap[ri * OUT_D +  0 + lo] = c0[q];
    ap[ri * OUT_D + 16 + lo] = c1[q];
    ap[ri * OUT_D + 32 + lo] = c2[q];
    ap[ri * OUT_D + 48 + lo] = c3[q];
  }
}

// ---------------- Kernel 4: combine partitions, normalize (float4-vectorized) -------
__global__ __launch_bounds__(256) void k_combine(
    const float* __restrict__ accp, const float* __restrict__ lpart,
    float* __restrict__ out, int npart)
{
  int idx4 = blockIdx.x * 256 + threadIdx.x;   // each handles 4 floats
  int i = idx4 >> 4;                           // row (16 float4 per row of 64)
  float4 s = {0.f, 0.f, 0.f, 0.f};
  float li = 0.f;
  for (int p = 0; p < npart; ++p) {
    float4 v = *(const float4*)(accp + (size_t)p * (NN * OUT_D) + (size_t)idx4 * 4);
    s.x += v.x; s.y += v.y; s.z += v.z; s.w += v.w;
    li += lpart[(size_t)p * NN + i];
  }
  float r = 1.0f / li;
  s.x *= r; s.y *= r; s.z *= r; s.w *= r;
  *(float4*)(out + (size_t)idx4 * 4) = s;
}

extern "C" void kernel_launch(void* const* d_in, const int* in_sizes, int n_in,
                              void* d_out, int out_size, void* d_ws, size_t ws_size,
                              hipStream_t stream)
{
  const float* X   = (const float*)d_in[0];
  const int*   adj = (const int*)d_in[1];
  const float* W   = (const float*)d_in[2];
  const float* a   = (const float*)d_in[3];
  float* out = (float*)d_out;

  char* ws = (char*)d_ws;
  size_t off = 0;
  float* s1  = (float*)(ws + off); off += NN * 4;
  float* s2  = (float*)(ws + off); off += NN * 4;
  unsigned* s2key = (unsigned*)(ws + off); off += 64;
  short* hbT = (short*)(ws + off); off += (size_t)OUT_D * NN * 2;   // 512 KB
  short* Ahi = (short*)(ws + off); off += 4096 * 8 * 2;             // 64 KB
  short* Alo = (short*)(ws + off); off += 4096 * 8 * 2;             // 64 KB
  size_t fixed = off;

  size_t per_part = (size_t)(NN * OUT_D + NN) * 4;
  int npart = 1;
  for (int p = 16; p >= 1; p >>= 1)
    if (fixed + (size_t)p * per_part <= ws_size) { npart = p; break; }
  float* accp  = (float*)(ws + fixed);
  float* lpart = (float*)(ws + fixed + (size_t)npart * NN * OUT_D * 4);

  k_wpack<<<16, 256, 0, stream>>>(W, Ahi, Alo, s2key);
  k_h_mfma<<<NN / 16, 256, 0, stream>>>(X, Ahi, Alo, a, hbT, s1, s2, s2key);
  dim3 grid_attn(NN / 64, npart);
  if (npart == 16)
    k_attn<256><<<grid_attn, 256, 0, stream>>>(adj, hbT, s1, s2, s2key, accp, lpart);
  else if (npart == 8)
    k_attn<512><<<grid_attn, 256, 0, stream>>>(adj, hbT, s1, s2, s2key, accp, lpart);
  else
    k_attn_rt<<<grid_attn, 256, 0, stream>>>(adj, hbT, s1, s2, s2key, accp, lpart, NN / npart);
  k_combine<<<(NN * OUT_D) / (256 * 4), 256, 0, stream>>>(accp, lpart, out, npart);
}